// Round 6
// baseline (381.012 us; speedup 1.0000x reference)
//
#include <hip/hip_runtime.h>
#include <math.h>

typedef _Float16 half8 __attribute__((ext_vector_type(8)));
typedef _Float16 half4 __attribute__((ext_vector_type(4)));
typedef float f32x4 __attribute__((ext_vector_type(4)));

constexpr int IN    = 256;
constexpr int HEADS = 4;
constexpr int HID   = 64;
constexpr int NCLS  = 47;
constexpr int HD0   = 256;
constexpr int HD1   = 188;
constexpr float NEG_SLOPE = 0.2f;
constexpr int ND0 = 50000, ND1 = 10000;

static __device__ __forceinline__ float leaky(float x) {
    return x >= 0.f ? x : NEG_SLOPE * x;
}

__device__ __forceinline__ void gload16(const void* g, void* l) {
    __builtin_amdgcn_global_load_lds((const __attribute__((address_space(1))) void*)g,
                                     (__attribute__((address_space(3))) void*)l, 16, 0, 0);
}

// vT[h*IN + k] = sum_d W[k, h*D+d] * attn[h,d]
__global__ void make_vT(const float* __restrict__ W, const float* __restrict__ attn,
                        float* __restrict__ vT, int D) {
    int id = blockIdx.x * blockDim.x + threadIdx.x;
    if (id >= IN * HEADS) return;
    int k = id >> 2, h = id & 3;
    const float* wr = W + (size_t)k * (HEADS * D) + h * D;
    const float* ar = attn + h * D;
    float s = 0.f;
    for (int d = 0; d < D; ++d) s += wr[d] * ar[d];
    vT[h * IN + k] = s;
}

// Bt[n][k] = (n < N) ? (f16)W[k*N+n] : 0 ;  Bt is [BROWS][IN]
__global__ void cvtB(const float* __restrict__ W, _Float16* __restrict__ Bt, int N, int BROWS) {
    int id = blockIdx.x * 256 + threadIdx.x;
    if (id >= BROWS * IN) return;
    int n = id / IN, k = id % IN;
    Bt[id] = (n < N) ? (_Float16)W[(size_t)k * N + n] : (_Float16)0.f;
}

// Persistent streaming MFMA GEMM. B (BCOLS x 256 f16) staged to LDS ONCE per
// block (swizzled, conflict-free — PMC-verified in r5), then a barrier-free
// tile loop: each wave owns 16-row tiles, A prefetched to registers with an
// explicit 2-buffer pipeline + sched_barrier(0) fences so loads can't be sunk.
template <bool AHALF, int BCOLS, int NOUT, bool ZHALF, int FEL>
__global__ __launch_bounds__(512, 2) void gemm_persist(const void* __restrict__ Av,
        const _Float16* __restrict__ Bt, void* __restrict__ Z,
        const float* __restrict__ attn_flat, float* __restrict__ el, int M, int ntiles) {
    constexpr int FN = BCOLS / 16;
    __shared__ __align__(16) _Float16 Bs[BCOLS * 256];
    const int t = threadIdx.x;
    const int l = t & 63, w = t >> 6;
    const int lr = l & 15, lh = l >> 4;
    const int G = gridDim.x;

    // ---- stage B once ----
    constexpr int ITERS = (BCOLS * 32) / 512;
#pragma unroll
    for (int it = 0; it < ITERS; ++it) {
        int c = it * 512 + t;
        int r = c >> 5, s = c & 31;
        int cs = s ^ (((r & 15) << 1) ^ ((r >> 4) & 1));
        gload16(Bt + (size_t)r * IN + cs * 8, (char*)Bs + (it * 512 + w * 64) * 16);
    }
    __syncthreads();   // only barrier in the kernel

    float alv[FN];
    if constexpr (FEL > 0) {
#pragma unroll
        for (int nj = 0; nj < FN; ++nj) {
            int col = nj * 16 + lr;
            if constexpr (FEL == 1) alv[nj] = attn_flat[col];
            else                    alv[nj] = (col < NOUT) ? attn_flat[col] : 0.f;
        }
    }

    float4 fA0[8], fA1[8], fB0[8], fB1[8];
    half8  hA[8], hB[8];

    auto issue = [&](int tile, float4 (&x0)[8], float4 (&x1)[8], half8 (&xh)[8]) {
        int row = tile * 128 + w * 16 + lr;
        if (row >= M) row = M - 1;
        if constexpr (AHALF) {
            const _Float16* ap = (const _Float16*)Av + (size_t)row * IN + lh * 8;
#pragma unroll
            for (int tt = 0; tt < 8; ++tt) xh[tt] = *(const half8*)(ap + tt * 32);
        } else {
            const float* ap = (const float*)Av + (size_t)row * IN + lh * 8;
#pragma unroll
            for (int tt = 0; tt < 8; ++tt) {
                x0[tt] = *(const float4*)(ap + tt * 32);
                x1[tt] = *(const float4*)(ap + tt * 32 + 4);
            }
        }
        __builtin_amdgcn_sched_barrier(0);   // don't sink these loads
    };

    const int swz_l = lr << 1;
    auto compute_store = [&](int tile, float4 (&x0)[8], float4 (&x1)[8], half8 (&xh)[8]) {
        f32x4 acc[FN];
#pragma unroll
        for (int nj = 0; nj < FN; ++nj) {
            acc[nj][0] = 0.f; acc[nj][1] = 0.f; acc[nj][2] = 0.f; acc[nj][3] = 0.f;
        }
#pragma unroll
        for (int tt = 0; tt < 8; ++tt) {
            half8 af;
            if constexpr (AHALF) {
                af = xh[tt];
            } else {
                af[0] = (_Float16)x0[tt].x; af[1] = (_Float16)x0[tt].y;
                af[2] = (_Float16)x0[tt].z; af[3] = (_Float16)x0[tt].w;
                af[4] = (_Float16)x1[tt].x; af[5] = (_Float16)x1[tt].y;
                af[6] = (_Float16)x1[tt].z; af[7] = (_Float16)x1[tt].w;
            }
#pragma unroll
            for (int nj = 0; nj < FN; ++nj) {
                int colr = nj * 16 + lr;
                int slot = (tt * 4 + lh) ^ swz_l ^ (nj & 1);
                half8 bf = *(const half8*)&Bs[colr * 256 + slot * 8];
                acc[nj] = __builtin_amdgcn_mfma_f32_16x16x32_f16(af, bf, acc[nj], 0, 0, 0);
            }
        }
        const int R0 = tile * 128 + w * 16;
#pragma unroll
        for (int r = 0; r < 4; ++r) {
            int grow = R0 + lh * 4 + r;
            if (grow < M) {
#pragma unroll
                for (int nj = 0; nj < FN; ++nj) {
                    int col = nj * 16 + lr;
                    if (col < NOUT) {
                        if constexpr (ZHALF)
                            ((_Float16*)Z)[(size_t)grow * NOUT + col] = (_Float16)acc[nj][r];
                        else
                            ((float*)Z)[(size_t)grow * NOUT + col] = acc[nj][r];
                    }
                }
            }
        }
        if constexpr (FEL > 0) {
#pragma unroll
            for (int r = 0; r < 4; ++r) {
                float sh0 = 0.f, sh1 = 0.f, sh2 = 0.f, sh3 = 0.f;
#pragma unroll
                for (int nj = 0; nj < FN; ++nj) {
                    float v = acc[nj][r] * alv[nj];
                    if constexpr (FEL == 1) {
                        switch (nj >> 2) {
                            case 0: sh0 += v; break;
                            case 1: sh1 += v; break;
                            case 2: sh2 += v; break;
                            default: sh3 += v; break;
                        }
                    } else {
                        int col = nj * 16 + lr;
                        int hs = col < 47 ? 0 : col < 94 ? 1 : col < 141 ? 2 : 3;
                        sh0 += (hs == 0) ? v : 0.f;
                        sh1 += (hs == 1) ? v : 0.f;
                        sh2 += (hs == 2) ? v : 0.f;
                        sh3 += (hs == 3) ? v : 0.f;
                    }
                }
#pragma unroll
                for (int off = 1; off <= 8; off <<= 1) {
                    sh0 += __shfl_xor(sh0, off); sh1 += __shfl_xor(sh1, off);
                    sh2 += __shfl_xor(sh2, off); sh3 += __shfl_xor(sh3, off);
                }
                int grow = R0 + lh * 4 + r;
                if (lr == 0 && grow < M)
                    *(float4*)(el + (size_t)grow * 4) = make_float4(sh0, sh1, sh2, sh3);
            }
        }
    };

    int t0 = blockIdx.x;
    if (t0 < ntiles) issue(t0, fA0, fA1, hA);
    for (int tt0 = t0; tt0 < ntiles; tt0 += 2 * G) {
        int t1 = tt0 + G;
        if (t1 < ntiles) issue(t1, fB0, fB1, hB);
        compute_store(tt0, fA0, fA1, hA);
        int t2 = tt0 + 2 * G;
        if (t2 < ntiles) issue(t2, fA0, fA1, hA);
        if (t1 < ntiles) compute_store(t1, fB0, fB1, hB);
    }
}

// er[m,h] = x[m,:] @ vrT[h,:]  (fp32 A); one wave per row
__global__ __launch_bounds__(256) void gemv_er_f32(const float* __restrict__ A,
        const float* __restrict__ vrT, float* __restrict__ er, int M) {
    int wv = threadIdx.x >> 6, lane = threadIdx.x & 63;
    int row = blockIdx.x * 4 + wv;
    if (row >= M) return;
    float4 xa = *(const float4*)(A + (size_t)row * IN + lane * 4);
    float s[4];
#pragma unroll
    for (int h = 0; h < 4; ++h) {
        float4 v = *(const float4*)(vrT + h * IN + lane * 4);
        s[h] = xa.x * v.x + xa.y * v.y + xa.z * v.z + xa.w * v.w;
    }
#pragma unroll
    for (int off = 32; off; off >>= 1)
#pragma unroll
        for (int h = 0; h < 4; ++h) s[h] += __shfl_xor(s[h], off);
    if (lane == 0) *(float4*)(er + (size_t)row * 4) = make_float4(s[0], s[1], s[2], s[3]);
}

// er from f16 A, rows < M
__global__ __launch_bounds__(256) void gemv_er_f16(const _Float16* __restrict__ A,
        const float* __restrict__ vrT, float* __restrict__ er, int M) {
    int wv = threadIdx.x >> 6, lane = threadIdx.x & 63;
    int row = blockIdx.x * 4 + wv;
    if (row >= M) return;
    half4 ah = *(const half4*)(A + (size_t)row * IN + lane * 4);
    float a0 = (float)ah[0], a1 = (float)ah[1], a2 = (float)ah[2], a3 = (float)ah[3];
    float s[4];
#pragma unroll
    for (int h = 0; h < 4; ++h) {
        float4 v = *(const float4*)(vrT + h * IN + lane * 4);
        s[h] = a0 * v.x + a1 * v.y + a2 * v.z + a3 * v.w;
    }
#pragma unroll
    for (int off = 32; off; off >>= 1)
#pragma unroll
        for (int h = 0; h < 4; ++h) s[h] += __shfl_xor(s[h], off);
    if (lane == 0) *(float4*)(er + (size_t)row * 4) = make_float4(s[0], s[1], s[2], s[3]);
}

__global__ void hist_k(const int* __restrict__ dst, int E, int* __restrict__ counts) {
    int i = blockIdx.x * blockDim.x + threadIdx.x;
    if (i < E) atomicAdd(&counts[dst[i]], 1);
}

// ---- 3-kernel parallel exclusive scan ----
__global__ __launch_bounds__(256) void scan1_k(const int* __restrict__ counts, int n,
                                               int* __restrict__ part) {
    __shared__ int ws[4];
    int i = blockIdx.x * 256 + threadIdx.x;
    int lane = threadIdx.x & 63, wv = threadIdx.x >> 6;
    int s = (i < n) ? counts[i] : 0;
#pragma unroll
    for (int off = 32; off; off >>= 1) s += __shfl_xor(s, off);
    if (lane == 0) ws[wv] = s;
    __syncthreads();
    if (threadIdx.x == 0) part[blockIdx.x] = ws[0] + ws[1] + ws[2] + ws[3];
}

__global__ __launch_bounds__(256) void scan2_k(int* __restrict__ part, int nb) {
    __shared__ int ws[4];
    int tid = threadIdx.x, lane = tid & 63, wv = tid >> 6;
    int v = (tid < nb) ? part[tid] : 0;
    int x = v;
#pragma unroll
    for (int off = 1; off < 64; off <<= 1) {
        int u = __shfl_up(x, off);
        if (lane >= off) x += u;
    }
    if (lane == 63) ws[wv] = x;
    __syncthreads();
    int base = 0;
    for (int k = 0; k < wv; ++k) base += ws[k];
    if (tid < nb) part[tid] = base + x - v;
}

__global__ __launch_bounds__(256) void scan3_k(const int* __restrict__ counts, int n,
        const int* __restrict__ part, int* __restrict__ offsets, int* __restrict__ cursor) {
    __shared__ int ws[4];
    int i = blockIdx.x * 256 + threadIdx.x;
    int lane = threadIdx.x & 63, wv = threadIdx.x >> 6;
    int v = (i < n) ? counts[i] : 0;
    int x = v;
#pragma unroll
    for (int off = 1; off < 64; off <<= 1) {
        int u = __shfl_up(x, off);
        if (lane >= off) x += u;
    }
    if (lane == 63) ws[wv] = x;
    __syncthreads();
    int base = part[blockIdx.x];
    for (int k = 0; k < wv; ++k) base += ws[k];
    int off_ = base + x - v;
    if (i < n) { offsets[i] = off_; cursor[i] = off_; }
    if (i == n - 1) offsets[n] = off_ + v;
}

__global__ void scatter_k(const int* __restrict__ src, const int* __restrict__ dst, int E,
        int* __restrict__ cursor, int* __restrict__ ssrc) {
    int i = blockIdx.x * blockDim.x + threadIdx.x;
    if (i < E) {
        int p = atomicAdd(&cursor[dst[i]], 1);
        ssrc[p] = src[i];
    }
}

// Layer-0 aggregation: 4 waves/block, 1 node/wave, edge loop unrolled x4 for ILP
__global__ __launch_bounds__(256) void agg_l0(const int* __restrict__ ssrc,
        const int* __restrict__ offs, const float* __restrict__ el,
        const float* __restrict__ er, const _Float16* __restrict__ z,
        const float* __restrict__ bias, _Float16* __restrict__ h, int nd) {
    int wv = threadIdx.x >> 6, lane = threadIdx.x & 63;
    int d = blockIdx.x * 4 + wv;
    if (d >= nd) return;
    int head = lane >> 4;
    int beg = offs[d], end = offs[d + 1];
    float erh = er[(size_t)d * 4 + head];
    float ax = 0, ay = 0, az = 0, aw = 0, ssum = 0;
    for (int j0 = beg; j0 < end; j0 += 64) {
        int nn = min(64, end - j0);
        int myidx = (lane < nn) ? ssrc[j0 + lane] : 0;
        int j = 0;
        for (; j + 4 <= nn; j += 4) {
            int s0 = __shfl(myidx, j),     s1 = __shfl(myidx, j + 1);
            int s2 = __shfl(myidx, j + 2), s3 = __shfl(myidx, j + 3);
            float e0 = el[(size_t)s0 * 4 + head], e1 = el[(size_t)s1 * 4 + head];
            float e2 = el[(size_t)s2 * 4 + head], e3 = el[(size_t)s3 * 4 + head];
            half4 zv0 = *(const half4*)(z + (size_t)s0 * HD0 + lane * 4);
            half4 zv1 = *(const half4*)(z + (size_t)s1 * HD0 + lane * 4);
            half4 zv2 = *(const half4*)(z + (size_t)s2 * HD0 + lane * 4);
            half4 zv3 = *(const half4*)(z + (size_t)s3 * HD0 + lane * 4);
            float w0 = __expf(leaky(e0 + erh)), w1 = __expf(leaky(e1 + erh));
            float w2 = __expf(leaky(e2 + erh)), w3 = __expf(leaky(e3 + erh));
            ssum += (w0 + w1) + (w2 + w3);
            ax += w0 * (float)zv0[0] + w1 * (float)zv1[0] + w2 * (float)zv2[0] + w3 * (float)zv3[0];
            ay += w0 * (float)zv0[1] + w1 * (float)zv1[1] + w2 * (float)zv2[1] + w3 * (float)zv3[1];
            az += w0 * (float)zv0[2] + w1 * (float)zv1[2] + w2 * (float)zv2[2] + w3 * (float)zv3[2];
            aw += w0 * (float)zv0[3] + w1 * (float)zv1[3] + w2 * (float)zv2[3] + w3 * (float)zv3[3];
        }
        for (; j < nn; ++j) {
            int s = __shfl(myidx, j);
            float e = el[(size_t)s * 4 + head] + erh;
            float wgt = __expf(leaky(e));
            ssum += wgt;
            half4 zv = *(const half4*)(z + (size_t)s * HD0 + lane * 4);
            ax += wgt * (float)zv[0]; ay += wgt * (float)zv[1];
            az += wgt * (float)zv[2]; aw += wgt * (float)zv[3];
        }
    }
    float inv = ssum > 0.f ? 1.f / ssum : 0.f;
    const float* b = bias + lane * 4;
    half4 o;
    o[0] = (_Float16)fmaxf(ax * inv + b[0], 0.f);
    o[1] = (_Float16)fmaxf(ay * inv + b[1], 0.f);
    o[2] = (_Float16)fmaxf(az * inv + b[2], 0.f);
    o[3] = (_Float16)fmaxf(aw * inv + b[3], 0.f);
    *(half4*)(h + (size_t)d * HD0 + lane * 4) = o;
}

// Layer-1 aggregation: 4 waves/block, 1 node/wave, unrolled x2
__global__ __launch_bounds__(256) void agg_l1(const int* __restrict__ ssrc,
        const int* __restrict__ offs, const float* __restrict__ el,
        const float* __restrict__ er, const float* __restrict__ z,
        const float* __restrict__ bias, float* __restrict__ out, int nd) {
    int wv = threadIdx.x >> 6, lane = threadIdx.x & 63;
    int d = blockIdx.x * 4 + wv;
    if (d >= nd) return;
    int beg = offs[d], end = offs[d + 1];
    float4 er4 = *(const float4*)(er + (size_t)d * 4);
    const int f0 = lane, f1 = lane + 64, f2 = lane + 128;
    const int h0 = f0 / NCLS, h1 = f1 / NCLS;
    const bool has2 = f2 < HD1;
    const int h2 = has2 ? f2 / NCLS : 3;
    float a0 = 0, a1 = 0, a2 = 0;
    float s0 = 0, s1 = 0, s2 = 0, s3 = 0;
    for (int j0 = beg; j0 < end; j0 += 64) {
        int nn = min(64, end - j0);
        int myidx = (lane < nn) ? ssrc[j0 + lane] : 0;
        int j = 0;
        for (; j + 2 <= nn; j += 2) {
            int sa_ = __shfl(myidx, j), sb_ = __shfl(myidx, j + 1);
            float4 ea = *(const float4*)(el + (size_t)sa_ * 4);
            float4 eb = *(const float4*)(el + (size_t)sb_ * 4);
            const float* za = z + (size_t)sa_ * HD1;
            const float* zb = z + (size_t)sb_ * HD1;
            float za0 = za[f0], za1 = za[f1], za2 = has2 ? za[f2] : 0.f;
            float zb0 = zb[f0], zb1 = zb[f1], zb2 = has2 ? zb[f2] : 0.f;
            float wa0 = __expf(leaky(ea.x + er4.x)), wa1 = __expf(leaky(ea.y + er4.y));
            float wa2 = __expf(leaky(ea.z + er4.z)), wa3 = __expf(leaky(ea.w + er4.w));
            float wb0 = __expf(leaky(eb.x + er4.x)), wb1 = __expf(leaky(eb.y + er4.y));
            float wb2 = __expf(leaky(eb.z + er4.z)), wb3 = __expf(leaky(eb.w + er4.w));
            s0 += wa0 + wb0; s1 += wa1 + wb1; s2 += wa2 + wb2; s3 += wa3 + wb3;
            a0 += (h0 == 0 ? wa0 : h0 == 1 ? wa1 : h0 == 2 ? wa2 : wa3) * za0
                + (h0 == 0 ? wb0 : h0 == 1 ? wb1 : h0 == 2 ? wb2 : wb3) * zb0;
            a1 += (h1 == 0 ? wa0 : h1 == 1 ? wa1 : h1 == 2 ? wa2 : wa3) * za1
                + (h1 == 0 ? wb0 : h1 == 1 ? wb1 : h1 == 2 ? wb2 : wb3) * zb1;
            if (has2)
                a2 += (h2 == 0 ? wa0 : h2 == 1 ? wa1 : h2 == 2 ? wa2 : wa3) * za2
                    + (h2 == 0 ? wb0 : h2 == 1 ? wb1 : h2 == 2 ? wb2 : wb3) * zb2;
        }
        for (; j < nn; ++j) {
            int s = __shfl(myidx, j);
            float4 e4 = *(const float4*)(el + (size_t)s * 4);
            float w0 = __expf(leaky(e4.x + er4.x));
            float w1 = __expf(leaky(e4.y + er4.y));
            float w2 = __expf(leaky(e4.z + er4.z));
            float w3 = __expf(leaky(e4.w + er4.w));
            s0 += w0; s1 += w1; s2 += w2; s3 += w3;
            const float* zr = z + (size_t)s * HD1;
            a0 += (h0 == 0 ? w0 : h0 == 1 ? w1 : h0 == 2 ? w2 : w3) * zr[f0];
            a1 += (h1 == 0 ? w0 : h1 == 1 ? w1 : h1 == 2 ? w2 : w3) * zr[f1];
            if (has2) a2 += (h2 == 0 ? w0 : h2 == 1 ? w1 : h2 == 2 ? w2 : w3) * zr[f2];
        }
    }
    float sa = h0 == 0 ? s0 : h0 == 1 ? s1 : h0 == 2 ? s2 : s3;
    float sb = h1 == 0 ? s0 : h1 == 1 ? s1 : h1 == 2 ? s2 : s3;
    float sc = h2 == 0 ? s0 : h2 == 1 ? s1 : h2 == 2 ? s2 : s3;
    float* orow = out + (size_t)d * HD1;
    orow[f0] = a0 * (sa > 0.f ? 1.f / sa : 0.f) + bias[f0];
    orow[f1] = a1 * (sb > 0.f ? 1.f / sb : 0.f) + bias[f1];
    if (has2) orow[f2] = a2 * (sc > 0.f ? 1.f / sc : 0.f) + bias[f2];
}

// mean over heads + log_softmax; one wave per node
__global__ __launch_bounds__(256) void final_k(const float* __restrict__ o1,
        float* __restrict__ y, int n) {
    int wave = threadIdx.x >> 6, lane = threadIdx.x & 63;
    int node = blockIdx.x * 4 + wave;
    if (node >= n) return;
    const float* r = o1 + (size_t)node * HD1;
    float vv = 0.f, v = -INFINITY;
    if (lane < NCLS) {
        vv = 0.25f * (r[lane] + r[lane + NCLS] + r[lane + 2 * NCLS] + r[lane + 3 * NCLS]);
        v = vv;
    }
    float mx = v;
#pragma unroll
    for (int off = 32; off; off >>= 1) mx = fmaxf(mx, __shfl_xor(mx, off));
    float p = (lane < NCLS) ? __expf(vv - mx) : 0.f;
    float sum = p;
#pragma unroll
    for (int off = 32; off; off >>= 1) sum += __shfl_xor(sum, off);
    if (lane < NCLS) y[(size_t)node * NCLS + lane] = vv - mx - logf(sum);
}

extern "C" void kernel_launch(void* const* d_in, const int* in_sizes, int n_in,
                              void* d_out, int out_size, void* d_ws, size_t ws_size,
                              hipStream_t stream) {
    const float* x    = (const float*)d_in[0];
    const int*   src0 = (const int*)d_in[1];
    const int*   dst0 = (const int*)d_in[2];
    const int*   src1 = (const int*)d_in[3];
    const int*   dst1 = (const int*)d_in[4];
    const float* W0s  = (const float*)d_in[7];
    const float* W0d  = (const float*)d_in[8];
    const float* al0  = (const float*)d_in[9];
    const float* ar0  = (const float*)d_in[10];
    const float* b0   = (const float*)d_in[11];
    const float* W1s  = (const float*)d_in[12];
    const float* W1d  = (const float*)d_in[13];
    const float* al1  = (const float*)d_in[14];
    const float* ar1  = (const float*)d_in[15];
    const float* b1   = (const float*)d_in[16];
    const int E0 = in_sizes[1], E1 = in_sizes[3];
    const int NS0 = in_sizes[0] / IN;

    char* p = (char*)d_ws;
    auto take = [&](size_t bytes) {
        char* r = p;
        p += (bytes + 255) & ~(size_t)255;
        return r;
    };
    _Float16* z0  = (_Float16*)take((size_t)NS0 * HD0 * 2);
    _Float16* h   = (_Float16*)take((size_t)ND0 * HD0 * 2);
    float*    z1  = (float*)take((size_t)ND0 * HD1 * 4);
    float*    o1  = (float*)take((size_t)ND1 * HD1 * 4);
    float*    el0 = (float*)take((size_t)NS0 * 4 * 4);
    float*    er0 = (float*)take((size_t)ND0 * 4 * 4);
    float*    el1 = (float*)take((size_t)ND0 * 4 * 4);
    float*    er1 = (float*)take((size_t)ND1 * 4 * 4);
    _Float16* B0t = (_Float16*)take((size_t)256 * IN * 2);
    _Float16* B1t = (_Float16*)take((size_t)192 * IN * 2);
    float*    vr0T = (float*)take(4 * IN * 4);
    float*    vr1T = (float*)take(4 * IN * 4);
    int* counts0 = (int*)take((size_t)ND0 * 4);
    int* offs0   = (int*)take((size_t)(ND0 + 1) * 4);
    int* cur0    = (int*)take((size_t)ND0 * 4);
    int* ss0     = (int*)take((size_t)E0 * 4);
    int* counts1 = (int*)take((size_t)ND1 * 4);
    int* offs1   = (int*)take((size_t)(ND1 + 1) * 4);
    int* cur1    = (int*)take((size_t)ND1 * 4);
    int* ss1     = (int*)take((size_t)E1 * 4);
    int* part0   = (int*)take(256 * 4);
    int* part1   = (int*)take(256 * 4);

    const int NB0 = (ND0 + 255) / 256, NB1 = (ND1 + 255) / 256;
    const int NT0 = (NS0 + 127) / 128, NT1 = (ND0 + 127) / 128;

    hipMemsetAsync(counts0, 0, (size_t)ND0 * 4, stream);
    hipMemsetAsync(counts1, 0, (size_t)ND1 * 4, stream);

    make_vT<<<4, 256, 0, stream>>>(W0d, ar0, vr0T, HID);
    make_vT<<<4, 256, 0, stream>>>(W1d, ar1, vr1T, NCLS);
    cvtB<<<256, 256, 0, stream>>>(W0s, B0t, HD0, 256);
    cvtB<<<192, 256, 0, stream>>>(W1s, B1t, HD1, 192);

    // ---- layer 0 ----
    gemm_persist<false, 256, 256, true, 1><<<256, 512, 0, stream>>>(
        (const void*)x, B0t, (void*)z0, al0, el0, NS0, NT0);
    gemv_er_f32<<<(ND0 + 3) / 4, 256, 0, stream>>>(x, vr0T, er0, ND0);
    hist_k<<<(E0 + 255) / 256, 256, 0, stream>>>(dst0, E0, counts0);
    scan1_k<<<NB0, 256, 0, stream>>>(counts0, ND0, part0);
    scan2_k<<<1, 256, 0, stream>>>(part0, NB0);
    scan3_k<<<NB0, 256, 0, stream>>>(counts0, ND0, part0, offs0, cur0);
    scatter_k<<<(E0 + 255) / 256, 256, 0, stream>>>(src0, dst0, E0, cur0, ss0);
    agg_l0<<<(ND0 + 3) / 4, 256, 0, stream>>>(ss0, offs0, el0, er0, z0, b0, h, ND0);

    // ---- layer 1 ----
    gemm_persist<true, 192, 188, false, 2><<<256, 512, 0, stream>>>(
        (const void*)h, B1t, (void*)z1, al1, el1, ND0, NT1);
    gemv_er_f16<<<(ND1 + 3) / 4, 256, 0, stream>>>(h, vr1T, er1, ND1);
    hist_k<<<(E1 + 255) / 256, 256, 0, stream>>>(dst1, E1, counts1);
    scan1_k<<<NB1, 256, 0, stream>>>(counts1, ND1, part1);
    scan2_k<<<1, 256, 0, stream>>>(part1, NB1);
    scan3_k<<<NB1, 256, 0, stream>>>(counts1, ND1, part1, offs1, cur1);
    scatter_k<<<(E1 + 255) / 256, 256, 0, stream>>>(src1, dst1, E1, cur1, ss1);
    agg_l1<<<(ND1 + 3) / 4, 256, 0, stream>>>(ss1, offs1, el1, er1, z1, b1, o1, ND1);

    final_k<<<(ND1 + 3) / 4, 256, 0, stream>>>(o1, (float*)d_out, ND1);
}

// Round 7
// 302.367 us; speedup vs baseline: 1.2601x; 1.2601x over previous
//
#include <hip/hip_runtime.h>
#include <math.h>

typedef _Float16 half8 __attribute__((ext_vector_type(8)));
typedef _Float16 half4 __attribute__((ext_vector_type(4)));
typedef float f32x16 __attribute__((ext_vector_type(16)));

constexpr int IN    = 256;
constexpr int NCLS  = 47;
constexpr int HD1   = 188;
constexpr float NEG_SLOPE = 0.2f;
constexpr int ND0 = 50000, ND1 = 10000;

static __device__ __forceinline__ float leaky(float x) {
    return x >= 0.f ? x : NEG_SLOPE * x;
}

__device__ __forceinline__ void gload16(const void* g, void* l) {
    __builtin_amdgcn_global_load_lds((const __attribute__((address_space(1))) void*)g,
                                     (__attribute__((address_space(3))) void*)l, 16, 0, 0);
}

// ---------------- prep: weights->f16 (B^T layouts), folded attn vectors, permuted bias ----
// pc permutation (k-axis of layer-1 == col-axis of layer-0 outputs): c = ((pc&7)<<5)|(pc>>3)
__global__ __launch_bounds__(256) void prep_k(
        const float* __restrict__ W0s, const float* __restrict__ W1s,
        const float* __restrict__ W0d, const float* __restrict__ W1d,
        const float* __restrict__ ar0, const float* __restrict__ ar1,
        const float* __restrict__ b0,
        _Float16* __restrict__ B0t, _Float16* __restrict__ B1t,
        float* __restrict__ vr0T, float* __restrict__ vr1T, float* __restrict__ biasP) {
    int b = blockIdx.x, t = threadIdx.x;
    if (b < 256) {                       // B0t[n][k] = f16 W0s[k][n]
        int id = b * 256 + t;
        int n = id >> 8, k = id & 255;
        B0t[n * 256 + k] = (_Float16)W0s[(size_t)k * 256 + n];
    } else if (b < 448) {                // B1t[n][kpc] = f16 W1s[c(kpc)][n]
        int id = (b - 256) * 256 + t;
        int n = id >> 8, kpc = id & 255;
        int c = ((kpc & 7) << 5) | (kpc >> 3);
        B1t[n * 256 + kpc] = (n < HD1) ? (_Float16)W1s[(size_t)c * HD1 + n] : (_Float16)0.f;
    } else if (b == 448) {               // vr0T[h*256+k]
        for (int i = t; i < 1024; i += 256) {
            int h = i >> 8, k = i & 255;
            float s = 0.f;
            for (int d = 0; d < 64; ++d) s += W0d[(size_t)k * 256 + h * 64 + d] * ar0[h * 64 + d];
            vr0T[h * 256 + k] = s;
        }
    } else if (b == 449) {               // vr1T[h*256+kpc] (pc k-axis)
        for (int i = t; i < 1024; i += 256) {
            int h = i >> 8, kpc = i & 255;
            int c = ((kpc & 7) << 5) | (kpc >> 3);
            float s = 0.f;
            for (int d = 0; d < NCLS; ++d) s += W1d[(size_t)c * HD1 + h * NCLS + d] * ar1[h * NCLS + d];
            vr1T[h * 256 + kpc] = s;
        }
    } else {                             // biasP[pc] = b0[c(pc)]
        int c = ((t & 7) << 5) | (t >> 3);
        biasP[t] = b0[c];
    }
}

// ---------------- persistent 32x32x16 MFMA GEMM ----------------
// B (BCOLS x 256 f16) staged to LDS once per block; 8 waves, each owns 32 rows of a
// 256-row tile. A double-buffered per-wave through private LDS via global_load_lds
// (counted vmcnt, no barriers after the single B sync). ZPC: store z in pc layout
// (packed half8); else normal f32 with col mask. FEL 1: el heads = c>>6; FEL 2: c/47.
template <bool AHALF, int BCOLS, int NOUT, bool ZPC, int FEL>
__global__ __launch_bounds__(512, 2) void gemm32(const void* __restrict__ Av,
        const _Float16* __restrict__ Bt, void* __restrict__ Z,
        const float* __restrict__ attn_flat, float* __restrict__ el, int M, int ntiles) {
    constexpr int NCB  = BCOLS / 32;
    constexpr int ABUF = AHALF ? 1024 : 2048;   // bytes per K-step buffer (32 rows x 16 K)
    __shared__ __align__(16) _Float16 Bs[BCOLS * 256];
    __shared__ __align__(16) char As[8 * 2 * ABUF];
    const int t = threadIdx.x, l = t & 63, w = t >> 6;
    const int l31 = l & 31, hi = l >> 5;
    const int G = gridDim.x;
    char* Areg = As + w * 2 * ABUF;

    // stage B once (swizzled: slot' = slot ^ (col&7))
    constexpr int BITERS = (BCOLS * 32) / 512;
#pragma unroll
    for (int it = 0; it < BITERS; ++it) {
        int c = it * 512 + t;
        int col = c >> 5, sK = c & 31;
        int sKs = sK ^ (col & 7);
        gload16(Bt + (size_t)col * 256 + sKs * 8, (char*)Bs + (it * 512 + w * 64) * 16);
    }

    auto stageA = [&](int buf, int tile, int kst) {
        int base = tile * 256 + w * 32;
        if constexpr (AHALF) {
            int r = l >> 1, sl = l & 1;
            int row = base + r; if (row >= M) row = M - 1;
            int ks = sl ^ (r & 1);
            gload16((const _Float16*)Av + (size_t)row * 256 + kst * 16 + ks * 8,
                    Areg + buf * ABUF);
        } else {
#pragma unroll
            for (int i = 0; i < 2; ++i) {
                int c = i * 64 + l;
                int r = c >> 2, sl = c & 3;
                int row = base + r; if (row >= M) row = M - 1;
                int ks = sl ^ ((r >> 1) & 3);
                gload16((const float*)Av + (size_t)row * 256 + kst * 16 + ks * 4,
                        Areg + buf * ABUF + i * 1024);
            }
        }
    };

    int tile0 = blockIdx.x;
    stageA(0, tile0, 0);
    __syncthreads();     // drains B + first A buffer; only barrier in the kernel

    float alv[NCB];
    int hs[NCB];
    if constexpr (FEL > 0) {
#pragma unroll
        for (int cb = 0; cb < NCB; ++cb) {
            int c = cb * 32 + l31;
            if constexpr (FEL == 1) { alv[cb] = attn_flat[c]; hs[cb] = cb >> 1; }
            else { alv[cb] = (c < NOUT) ? attn_flat[c] : 0.f;
                   hs[cb] = c < 47 ? 0 : c < 94 ? 1 : c < 141 ? 2 : 3; }
        }
    }

    int buf = 0;
    for (int tile = tile0; tile < ntiles; tile += G) {
        f32x16 acc[NCB];
#pragma unroll
        for (int cb = 0; cb < NCB; ++cb)
#pragma unroll
            for (int e = 0; e < 16; ++e) acc[cb][e] = 0.f;

#pragma unroll
        for (int kst = 0; kst < 16; ++kst) {
            if (kst < 15) {
                stageA(buf ^ 1, tile, kst + 1);
                if constexpr (AHALF) asm volatile("s_waitcnt vmcnt(1)" ::: "memory");
                else                 asm volatile("s_waitcnt vmcnt(2)" ::: "memory");
            } else if (tile + G < ntiles) {
                stageA(buf ^ 1, tile + G, 0);
                if constexpr (AHALF) asm volatile("s_waitcnt vmcnt(1)" ::: "memory");
                else                 asm volatile("s_waitcnt vmcnt(2)" ::: "memory");
            } else {
                asm volatile("s_waitcnt vmcnt(0)" ::: "memory");
            }
            half8 af;
            if constexpr (AHALF) {
                af = *(const half8*)(Areg + buf * ABUF + l31 * 32 + ((hi ^ (l31 & 1)) << 4));
            } else {
                const char* ab = Areg + buf * ABUF + l31 * 64;
                float4 f0 = *(const float4*)(ab + ((( 2 * hi)     ^ ((l31 >> 1) & 3)) << 4));
                float4 f1 = *(const float4*)(ab + (((2 * hi + 1) ^ ((l31 >> 1) & 3)) << 4));
                af[0] = (_Float16)f0.x; af[1] = (_Float16)f0.y;
                af[2] = (_Float16)f0.z; af[3] = (_Float16)f0.w;
                af[4] = (_Float16)f1.x; af[5] = (_Float16)f1.y;
                af[6] = (_Float16)f1.z; af[7] = (_Float16)f1.w;
            }
#pragma unroll
            for (int cb = 0; cb < NCB; ++cb) {
                half8 bf = *(const half8*)&Bs[(cb * 32 + l31) * 256 +
                                              (((kst * 2 + hi) ^ (l & 7)) << 3)];
                acc[cb] = __builtin_amdgcn_mfma_f32_32x32x16_f16(af, bf, acc[cb], 0, 0, 0);
            }
            buf ^= 1;
        }

        // ---- epilogue: stores (C/D: col=l&31, row=(q&3)+8*(q>>2)+4*hi) ----
        const int R0 = tile * 256 + w * 32;
#pragma unroll
        for (int q = 0; q < 16; ++q) {
            int row = (q & 3) + 8 * (q >> 2) + 4 * hi;
            int grow = R0 + row;
            if constexpr (ZPC) {
                half8 hv;
#pragma unroll
                for (int cb = 0; cb < NCB; ++cb) hv[cb] = (_Float16)acc[cb][q];
                if (grow < M)
                    *(half8*)((_Float16*)Z + (size_t)grow * 256 + l31 * 8) = hv;
            } else {
                if (grow < M) {
#pragma unroll
                    for (int cb = 0; cb < NCB; ++cb) {
                        int col = cb * 32 + l31;
                        if (col < NOUT)
                            ((float*)Z)[(size_t)grow * NOUT + col] = acc[cb][q];
                    }
                }
            }
            if constexpr (FEL > 0) {
                float sh0 = 0.f, sh1 = 0.f, sh2 = 0.f, sh3 = 0.f;
#pragma unroll
                for (int cb = 0; cb < NCB; ++cb) {
                    float v = acc[cb][q] * alv[cb];
                    sh0 += (hs[cb] == 0) ? v : 0.f;
                    sh1 += (hs[cb] == 1) ? v : 0.f;
                    sh2 += (hs[cb] == 2) ? v : 0.f;
                    sh3 += (hs[cb] == 3) ? v : 0.f;
                }
#pragma unroll
                for (int off = 1; off <= 16; off <<= 1) {
                    sh0 += __shfl_xor(sh0, off); sh1 += __shfl_xor(sh1, off);
                    sh2 += __shfl_xor(sh2, off); sh3 += __shfl_xor(sh3, off);
                }
                if (l31 == 0 && grow < M)
                    *(float4*)(el + (size_t)grow * 4) = make_float4(sh0, sh1, sh2, sh3);
            }
        }
    }
}

// er[m,h] = x[m,:] @ vrT[h,:] (fp32 x, normal k); one wave per row
__global__ __launch_bounds__(256) void gemv_er_f32(const float* __restrict__ A,
        const float* __restrict__ vrT, float* __restrict__ er, int M) {
    int wv = threadIdx.x >> 6, lane = threadIdx.x & 63;
    int row = blockIdx.x * 4 + wv;
    if (row >= M) return;
    float4 xa = *(const float4*)(A + (size_t)row * IN + lane * 4);
    float s[4];
#pragma unroll
    for (int h = 0; h < 4; ++h) {
        float4 v = *(const float4*)(vrT + h * IN + lane * 4);
        s[h] = xa.x * v.x + xa.y * v.y + xa.z * v.z + xa.w * v.w;
    }
#pragma unroll
    for (int off = 32; off; off >>= 1)
#pragma unroll
        for (int h = 0; h < 4; ++h) s[h] += __shfl_xor(s[h], off);
    if (lane == 0) *(float4*)(er + (size_t)row * 4) = make_float4(s[0], s[1], s[2], s[3]);
}

// er from f16 h' (pc layout) with pc-indexed vrT
__global__ __launch_bounds__(256) void gemv_er_f16(const _Float16* __restrict__ A,
        const float* __restrict__ vrT, float* __restrict__ er, int M) {
    int wv = threadIdx.x >> 6, lane = threadIdx.x & 63;
    int row = blockIdx.x * 4 + wv;
    if (row >= M) return;
    half4 ah = *(const half4*)(A + (size_t)row * IN + lane * 4);
    float a0 = (float)ah[0], a1 = (float)ah[1], a2 = (float)ah[2], a3 = (float)ah[3];
    float s[4];
#pragma unroll
    for (int h = 0; h < 4; ++h) {
        float4 v = *(const float4*)(vrT + h * IN + lane * 4);
        s[h] = a0 * v.x + a1 * v.y + a2 * v.z + a3 * v.w;
    }
#pragma unroll
    for (int off = 32; off; off >>= 1)
#pragma unroll
        for (int h = 0; h < 4; ++h) s[h] += __shfl_xor(s[h], off);
    if (lane == 0) *(float4*)(er + (size_t)row * 4) = make_float4(s[0], s[1], s[2], s[3]);
}

// combined histogram over both layers' edges (counts = [ND0 | ND1])
__global__ void hist2_k(const int* __restrict__ dst0, int E0,
                        const int* __restrict__ dst1, int E1, int* __restrict__ counts) {
    int i = blockIdx.x * blockDim.x + threadIdx.x;
    if (i < E0) atomicAdd(&counts[dst0[i]], 1);
    else if (i < E0 + E1) atomicAdd(&counts[ND0 + dst1[i - E0]], 1);
}

// ---- 3-kernel parallel exclusive scan over counts[0..n) ----
__global__ __launch_bounds__(256) void scan1_k(const int* __restrict__ counts, int n,
                                               int* __restrict__ part) {
    __shared__ int ws[4];
    int i = blockIdx.x * 256 + threadIdx.x;
    int lane = threadIdx.x & 63, wv = threadIdx.x >> 6;
    int s = (i < n) ? counts[i] : 0;
#pragma unroll
    for (int off = 32; off; off >>= 1) s += __shfl_xor(s, off);
    if (lane == 0) ws[wv] = s;
    __syncthreads();
    if (threadIdx.x == 0) part[blockIdx.x] = ws[0] + ws[1] + ws[2] + ws[3];
}

__global__ __launch_bounds__(256) void scan2_k(int* __restrict__ part, int nb) {
    __shared__ int ws[4];
    int tid = threadIdx.x, lane = tid & 63, wv = tid >> 6;
    int v = (tid < nb) ? part[tid] : 0;
    int x = v;
#pragma unroll
    for (int off = 1; off < 64; off <<= 1) {
        int u = __shfl_up(x, off);
        if (lane >= off) x += u;
    }
    if (lane == 63) ws[wv] = x;
    __syncthreads();
    int base = 0;
    for (int k = 0; k < wv; ++k) base += ws[k];
    if (tid < nb) part[tid] = base + x - v;
}

__global__ __launch_bounds__(256) void scan3_k(const int* __restrict__ counts, int n,
        const int* __restrict__ part, int* __restrict__ offsets, int* __restrict__ cursor) {
    __shared__ int ws[4];
    int i = blockIdx.x * 256 + threadIdx.x;
    int lane = threadIdx.x & 63, wv = threadIdx.x >> 6;
    int v = (i < n) ? counts[i] : 0;
    int x = v;
#pragma unroll
    for (int off = 1; off < 64; off <<= 1) {
        int u = __shfl_up(x, off);
        if (lane >= off) x += u;
    }
    if (lane == 63) ws[wv] = x;
    __syncthreads();
    int base = part[blockIdx.x];
    for (int k = 0; k < wv; ++k) base += ws[k];
    int off_ = base + x - v;
    if (i < n) { offsets[i] = off_; cursor[i] = off_; }
    if (i == n - 1) offsets[n] = off_ + v;
}

__global__ void scatter2_k(const int* __restrict__ src0, const int* __restrict__ dst0, int E0,
                           const int* __restrict__ src1, const int* __restrict__ dst1, int E1,
                           int* __restrict__ cursor, int* __restrict__ ssrc) {
    int i = blockIdx.x * blockDim.x + threadIdx.x;
    if (i < E0) {
        int p = atomicAdd(&cursor[dst0[i]], 1);
        ssrc[p] = src0[i];
    } else if (i < E0 + E1) {
        int j = i - E0;
        int p = atomicAdd(&cursor[ND0 + dst1[j]], 1);
        ssrc[p] = src1[j];
    }
}

// Layer-0 aggregation on pc-layout z (head = 2*(l&1) + (e>>1) for lane's 4 slots)
__global__ __launch_bounds__(256) void agg_l0(const int* __restrict__ ssrc,
        const int* __restrict__ offs, const float* __restrict__ el,
        const float* __restrict__ er, const _Float16* __restrict__ z,
        const float* __restrict__ biasP, _Float16* __restrict__ h, int nd) {
    int wv = threadIdx.x >> 6, lane = threadIdx.x & 63;
    int d = blockIdx.x * 4 + wv;
    if (d >= nd) return;
    int beg = offs[d], end = offs[d + 1];
    float4 er4 = *(const float4*)(er + (size_t)d * 4);
    bool odd = lane & 1;
    float erlo = odd ? er4.z : er4.x;
    float erhi = odd ? er4.w : er4.y;
    float a0 = 0, a1 = 0, a2 = 0, a3 = 0, slo = 0, shi = 0;
    for (int j0 = beg; j0 < end; j0 += 64) {
        int nn = min(64, end - j0);
        int myidx = (lane < nn) ? ssrc[j0 + lane] : 0;
        int j = 0;
        for (; j + 4 <= nn; j += 4) {
            int s0 = __shfl(myidx, j),     s1 = __shfl(myidx, j + 1);
            int s2 = __shfl(myidx, j + 2), s3 = __shfl(myidx, j + 3);
            float4 e0 = *(const float4*)(el + (size_t)s0 * 4);
            float4 e1 = *(const float4*)(el + (size_t)s1 * 4);
            float4 e2 = *(const float4*)(el + (size_t)s2 * 4);
            float4 e3 = *(const float4*)(el + (size_t)s3 * 4);
            half4 z0v = *(const half4*)(z + (size_t)s0 * 256 + lane * 4);
            half4 z1v = *(const half4*)(z + (size_t)s1 * 256 + lane * 4);
            half4 z2v = *(const half4*)(z + (size_t)s2 * 256 + lane * 4);
            half4 z3v = *(const half4*)(z + (size_t)s3 * 256 + lane * 4);
            float wl0 = __expf(leaky((odd ? e0.z : e0.x) + erlo));
            float wh0 = __expf(leaky((odd ? e0.w : e0.y) + erhi));
            float wl1 = __expf(leaky((odd ? e1.z : e1.x) + erlo));
            float wh1 = __expf(leaky((odd ? e1.w : e1.y) + erhi));
            float wl2 = __expf(leaky((odd ? e2.z : e2.x) + erlo));
            float wh2 = __expf(leaky((odd ? e2.w : e2.y) + erhi));
            float wl3 = __expf(leaky((odd ? e3.z : e3.x) + erlo));
            float wh3 = __expf(leaky((odd ? e3.w : e3.y) + erhi));
            slo += (wl0 + wl1) + (wl2 + wl3);
            shi += (wh0 + wh1) + (wh2 + wh3);
            a0 += wl0 * (float)z0v[0] + wl1 * (float)z1v[0] + wl2 * (float)z2v[0] + wl3 * (float)z3v[0];
            a1 += wl0 * (float)z0v[1] + wl1 * (float)z1v[1] + wl2 * (float)z2v[1] + wl3 * (float)z3v[1];
            a2 += wh0 * (float)z0v[2] + wh1 * (float)z1v[2] + wh2 * (float)z2v[2] + wh3 * (float)z3v[2];
            a3 += wh0 * (float)z0v[3] + wh1 * (float)z1v[3] + wh2 * (float)z2v[3] + wh3 * (float)z3v[3];
        }
        for (; j < nn; ++j) {
            int s = __shfl(myidx, j);
            float4 e4 = *(const float4*)(el + (size_t)s * 4);
            half4 zv = *(const half4*)(z + (size_t)s * 256 + lane * 4);
            float wl = __expf(leaky((odd ? e4.z : e4.x) + erlo));
            float wh = __expf(leaky((odd ? e4.w : e4.y) + erhi));
            slo += wl; shi += wh;
            a0 += wl * (float)zv[0]; a1 += wl * (float)zv[1];
            a2 += wh * (float)zv[2]; a3 += wh * (float)zv[3];
        }
    }
    float ilo = slo > 0.f ? 1.f / slo : 0.f;
    float ihi = shi > 0.f ? 1.f / shi : 0.f;
    float4 b4 = *(const float4*)(biasP + lane * 4);
    half4 o;
    o[0] = (_Float16)fmaxf(a0 * ilo + b4.x, 0.f);
    o[1] = (_Float16)fmaxf(a1 * ilo + b4.y, 0.f);
    o[2] = (_Float16)fmaxf(a2 * ihi + b4.z, 0.f);
    o[3] = (_Float16)fmaxf(a3 * ihi + b4.w, 0.f);
    *(half4*)(h + (size_t)d * 256 + lane * 4) = o;
}

// Layer-1 aggregation (normal z1 layout) + fused head-mean + log_softmax
__global__ __launch_bounds__(256) void agg_l1f(const int* __restrict__ ssrc,
        const int* __restrict__ offs, const float* __restrict__ el,
        const float* __restrict__ er, const float* __restrict__ z,
        const float* __restrict__ bias, float* __restrict__ y, int nd) {
    __shared__ float ro[4][192];
    int wv = threadIdx.x >> 6, lane = threadIdx.x & 63;
    int d = blockIdx.x * 4 + wv;
    if (d >= nd) return;
    int beg = offs[ND0 + d], end = offs[ND0 + d + 1];
    float4 er4 = *(const float4*)(er + (size_t)d * 4);
    const int f0 = lane, f1 = lane + 64, f2 = lane + 128;
    const int h0 = f0 / NCLS, h1 = f1 / NCLS;
    const bool has2 = f2 < HD1;
    const int h2 = has2 ? f2 / NCLS : 3;
    float a0 = 0, a1 = 0, a2 = 0;
    float s0 = 0, s1 = 0, s2 = 0, s3 = 0;
    for (int j0 = beg; j0 < end; j0 += 64) {
        int nn = min(64, end - j0);
        int myidx = (lane < nn) ? ssrc[j0 + lane] : 0;
        int j = 0;
        for (; j + 2 <= nn; j += 2) {
            int sa_ = __shfl(myidx, j), sb_ = __shfl(myidx, j + 1);
            float4 ea = *(const float4*)(el + (size_t)sa_ * 4);
            float4 eb = *(const float4*)(el + (size_t)sb_ * 4);
            const float* za = z + (size_t)sa_ * HD1;
            const float* zb = z + (size_t)sb_ * HD1;
            float za0 = za[f0], za1 = za[f1], za2 = has2 ? za[f2] : 0.f;
            float zb0 = zb[f0], zb1 = zb[f1], zb2 = has2 ? zb[f2] : 0.f;
            float wa0 = __expf(leaky(ea.x + er4.x)), wa1 = __expf(leaky(ea.y + er4.y));
            float wa2 = __expf(leaky(ea.z + er4.z)), wa3 = __expf(leaky(ea.w + er4.w));
            float wb0 = __expf(leaky(eb.x + er4.x)), wb1 = __expf(leaky(eb.y + er4.y));
            float wb2 = __expf(leaky(eb.z + er4.z)), wb3 = __expf(leaky(eb.w + er4.w));
            s0 += wa0 + wb0; s1 += wa1 + wb1; s2 += wa2 + wb2; s3 += wa3 + wb3;
            a0 += (h0 == 0 ? wa0 : h0 == 1 ? wa1 : h0 == 2 ? wa2 : wa3) * za0
                + (h0 == 0 ? wb0 : h0 == 1 ? wb1 : h0 == 2 ? wb2 : wb3) * zb0;
            a1 += (h1 == 0 ? wa0 : h1 == 1 ? wa1 : h1 == 2 ? wa2 : wa3) * za1
                + (h1 == 0 ? wb0 : h1 == 1 ? wb1 : h1 == 2 ? wb2 : wb3) * zb1;
            if (has2)
                a2 += (h2 == 0 ? wa0 : h2 == 1 ? wa1 : h2 == 2 ? wa2 : wa3) * za2
                    + (h2 == 0 ? wb0 : h2 == 1 ? wb1 : h2 == 2 ? wb2 : wb3) * zb2;
        }
        for (; j < nn; ++j) {
            int s = __shfl(myidx, j);
            float4 e4 = *(const float4*)(el + (size_t)s * 4);
            float w0 = __expf(leaky(e4.x + er4.x));
            float w1 = __expf(leaky(e4.y + er4.y));
            float w2 = __expf(leaky(e4.z + er4.z));
            float w3 = __expf(leaky(e4.w + er4.w));
            s0 += w0; s1 += w1; s2 += w2; s3 += w3;
            const float* zr = z + (size_t)s * HD1;
            a0 += (h0 == 0 ? w0 : h0 == 1 ? w1 : h0 == 2 ? w2 : w3) * zr[f0];
            a1 += (h1 == 0 ? w0 : h1 == 1 ? w1 : h1 == 2 ? w2 : w3) * zr[f1];
            if (has2) a2 += (h2 == 0 ? w0 : h2 == 1 ? w1 : h2 == 2 ? w2 : w3) * zr[f2];
        }
    }
    float sa = h0 == 0 ? s0 : h0 == 1 ? s1 : h0 == 2 ? s2 : s3;
    float sb = h1 == 0 ? s0 : h1 == 1 ? s1 : h1 == 2 ? s2 : s3;
    float sc = h2 == 0 ? s0 : h2 == 1 ? s1 : h2 == 2 ? s2 : s3;
    ro[wv][f0] = a0 * (sa > 0.f ? 1.f / sa : 0.f) + bias[f0];
    ro[wv][f1] = a1 * (sb > 0.f ? 1.f / sb : 0.f) + bias[f1];
    if (has2) ro[wv][f2] = a2 * (sc > 0.f ? 1.f / sc : 0.f) + bias[f2];
    asm volatile("s_waitcnt lgkmcnt(0)" ::: "memory");
    __builtin_amdgcn_sched_barrier(0);
    // head-mean + log_softmax (wave-internal, no block barrier needed)
    float vv = 0.f, v = -INFINITY;
    if (lane < NCLS) {
        vv = 0.25f * (ro[wv][lane] + ro[wv][lane + NCLS] +
                      ro[wv][lane + 2 * NCLS] + ro[wv][lane + 3 * NCLS]);
        v = vv;
    }
    float mx = v;
#pragma unroll
    for (int off = 32; off; off >>= 1) mx = fmaxf(mx, __shfl_xor(mx, off));
    float pp = (lane < NCLS) ? __expf(vv - mx) : 0.f;
    float sum = pp;
#pragma unroll
    for (int off = 32; off; off >>= 1) sum += __shfl_xor(sum, off);
    if (lane < NCLS) y[(size_t)d * NCLS + lane] = vv - mx - logf(sum);
}

extern "C" void kernel_launch(void* const* d_in, const int* in_sizes, int n_in,
                              void* d_out, int out_size, void* d_ws, size_t ws_size,
                              hipStream_t stream) {
    const float* x    = (const float*)d_in[0];
    const int*   src0 = (const int*)d_in[1];
    const int*   dst0 = (const int*)d_in[2];
    const int*   src1 = (const int*)d_in[3];
    const int*   dst1 = (const int*)d_in[4];
    const float* W0s  = (const float*)d_in[7];
    const float* W0d  = (const float*)d_in[8];
    const float* al0  = (const float*)d_in[9];
    const float* ar0  = (const float*)d_in[10];
    const float* b0   = (const float*)d_in[11];
    const float* W1s  = (const float*)d_in[12];
    const float* W1d  = (const float*)d_in[13];
    const float* al1  = (const float*)d_in[14];
    const float* ar1  = (const float*)d_in[15];
    const float* b1   = (const float*)d_in[16];
    const int E0 = in_sizes[1], E1 = in_sizes[3];
    const int NS0 = in_sizes[0] / IN;

    char* p = (char*)d_ws;
    auto take = [&](size_t bytes) {
        char* r = p;
        p += (bytes + 255) & ~(size_t)255;
        return r;
    };
    _Float16* z0   = (_Float16*)take((size_t)NS0 * 256 * 2);
    _Float16* h    = (_Float16*)take((size_t)ND0 * 256 * 2);
    float*    z1   = (float*)take((size_t)ND0 * HD1 * 4);
    float*    el0  = (float*)take((size_t)NS0 * 4 * 4);
    float*    er0  = (float*)take((size_t)ND0 * 4 * 4);
    float*    el1  = (float*)take((size_t)ND0 * 4 * 4);
    float*    er1  = (float*)take((size_t)ND1 * 4 * 4);
    _Float16* B0t  = (_Float16*)take((size_t)256 * 256 * 2);
    _Float16* B1t  = (_Float16*)take((size_t)192 * 256 * 2);
    float*    vr0T = (float*)take(4 * 256 * 4);
    float*    vr1T = (float*)take(4 * 256 * 4);
    float*    biasP = (float*)take(256 * 4);
    const int NDT = ND0 + ND1;
    int* counts = (int*)take((size_t)NDT * 4);
    int* offs   = (int*)take((size_t)(NDT + 1) * 4);
    int* cur    = (int*)take((size_t)NDT * 4);
    int* ss     = (int*)take((size_t)(E0 + E1) * 4);
    int* part   = (int*)take(256 * 4);

    const int NB = (NDT + 255) / 256;
    const int NT0 = (NS0 + 255) / 256, NT1 = (ND0 + 255) / 256;
    const int G0 = NT0 < 256 ? NT0 : 256, G1 = NT1 < 256 ? NT1 : 256;

    hipMemsetAsync(counts, 0, (size_t)NDT * 4, stream);

    prep_k<<<451, 256, 0, stream>>>(W0s, W1s, W0d, W1d, ar0, ar1, b0,
                                    B0t, B1t, vr0T, vr1T, biasP);
    hist2_k<<<(E0 + E1 + 255) / 256, 256, 0, stream>>>(dst0, E0, dst1, E1, counts);
    scan1_k<<<NB, 256, 0, stream>>>(counts, NDT, part);
    scan2_k<<<1, 256, 0, stream>>>(part, NB);
    scan3_k<<<NB, 256, 0, stream>>>(counts, NDT, part, offs, cur);
    scatter2_k<<<(E0 + E1 + 255) / 256, 256, 0, stream>>>(src0, dst0, E0, src1, dst1, E1,
                                                          cur, ss);

    // ---- layer 0 ----
    gemm32<false, 256, 256, true, 1><<<G0, 512, 0, stream>>>(
        (const void*)x, B0t, (void*)z0, al0, el0, NS0, NT0);
    gemv_er_f32<<<(ND0 + 3) / 4, 256, 0, stream>>>(x, vr0T, er0, ND0);
    agg_l0<<<(ND0 + 3) / 4, 256, 0, stream>>>(ss, offs, el0, er0, z0, biasP, h, ND0);

    // ---- layer 1 ----
    gemm32<true, 192, 188, false, 2><<<G1, 512, 0, stream>>>(
        (const void*)h, B1t, (void*)z1, al1, el1, ND0, NT1);
    gemv_er_f16<<<(ND1 + 3) / 4, 256, 0, stream>>>(h, vr1T, er1, ND1);
    agg_l1f<<<(ND1 + 3) / 4, 256, 0, stream>>>(ss, offs, el1, er1, z1, b1,
                                               (float*)d_out, ND1);
}